// Round 7
// baseline (371.031 us; speedup 1.0000x reference)
//
#include <hip/hip_runtime.h>
#include <hip/hip_fp16.h>

#define N_NODES 100000
#define N_EDGES 1250000
#define C 64
#define SCAN_NB 391      // ceil(100000/256)
#define SHARD_SZ 12500   // N_NODES / 8 exactly
#define COHORT 128       // blocks per shard in bucket_kernel

// clang-native vectors: __builtin_nontemporal_* rejects HIP_vector_type
typedef int vint4 __attribute__((ext_vector_type(4)));
typedef float vfloat2 __attribute__((ext_vector_type(2)));

// ---------------- CSR build ----------------

// int4 + non-temporal loads: stream dst without polluting L2
__global__ void hist_kernel(const int* __restrict__ dst, int* __restrict__ cnt) {
    int q = blockIdx.x * blockDim.x + threadIdx.x;
    if (q < N_EDGES / 4) {
        vint4 d = __builtin_nontemporal_load(&((const vint4*)dst)[q]);
        atomicAdd(&cnt[d.x], 1);
        atomicAdd(&cnt[d.y], 1);
        atomicAdd(&cnt[d.z], 1);
        atomicAdd(&cnt[d.w], 1);
    }
}

__global__ void scan1_kernel(const int* __restrict__ cnt, int* __restrict__ partial) {
    __shared__ int s[256];
    int i = blockIdx.x * 256 + threadIdx.x;
    int v = (i < N_NODES) ? cnt[i] : 0;
    s[threadIdx.x] = v;
    __syncthreads();
    for (int off = 128; off > 0; off >>= 1) {
        if (threadIdx.x < off) s[threadIdx.x] += s[threadIdx.x + off];
        __syncthreads();
    }
    if (threadIdx.x == 0) partial[blockIdx.x] = s[0];
}

__global__ __launch_bounds__(512) void scan2_kernel(int* __restrict__ partial) {
    __shared__ int s[512];
    int t = threadIdx.x;
    s[t] = (t < SCAN_NB) ? partial[t] : 0;
    __syncthreads();
    for (int off = 1; off < 512; off <<= 1) {
        int v = (t >= off) ? s[t - off] : 0;
        __syncthreads();
        s[t] += v;
        __syncthreads();
    }
    if (t < SCAN_NB) partial[t] = s[t];
}

__global__ void scan3_kernel(const int* __restrict__ cnt, const int* __restrict__ partial,
                             int* __restrict__ offsets, int* __restrict__ cursor) {
    __shared__ int s[256];
    int i = blockIdx.x * 256 + threadIdx.x;
    int t = threadIdx.x;
    int v = (i < N_NODES) ? cnt[i] : 0;
    s[t] = v;
    __syncthreads();
    for (int off = 1; off < 256; off <<= 1) {
        int u = (t >= off) ? s[t - off] : 0;
        __syncthreads();
        s[t] += u;
        __syncthreads();
    }
    int excl = s[t] - v + (blockIdx.x ? partial[blockIdx.x - 1] : 0);
    if (i < N_NODES) {
        offsets[i] = excl;
        cursor[i] = excl;
    }
    if (i == 0) offsets[N_NODES] = N_EDGES;
}

// XCD-sharded counting-sort scatter. Streaming dst/src use non-temporal
// loads so they don't evict the dirty sorted_src lines accumulating in this
// XCD's L2 (that eviction was the residual 10x write amplification).
__global__ __launch_bounds__(256) void bucket_kernel(const int* __restrict__ src,
                                                     const int* __restrict__ dst,
                                                     int* __restrict__ cursor,
                                                     int* __restrict__ sorted_src) {
    const int shard = blockIdx.x & 7;
    const int cohort = blockIdx.x >> 3;
    const int lo = shard * SHARD_SZ;
    const int hi = lo + SHARD_SZ;
    const int NQ = N_EDGES / 4;  // 312500 exactly
    const vint4* dst4 = (const vint4*)dst;
    for (int q = cohort * 256 + threadIdx.x; q < NQ; q += COHORT * 256) {
        vint4 d = __builtin_nontemporal_load(&dst4[q]);
        int e = 4 * q;
        if (d.x >= lo && d.x < hi) {
            int pos = atomicAdd(&cursor[d.x], 1);
            sorted_src[pos] = __builtin_nontemporal_load(&src[e + 0]);
        }
        if (d.y >= lo && d.y < hi) {
            int pos = atomicAdd(&cursor[d.y], 1);
            sorted_src[pos] = __builtin_nontemporal_load(&src[e + 1]);
        }
        if (d.z >= lo && d.z < hi) {
            int pos = atomicAdd(&cursor[d.z], 1);
            sorted_src[pos] = __builtin_nontemporal_load(&src[e + 2]);
        }
        if (d.w >= lo && d.w < hi) {
            int pos = atomicAdd(&cursor[d.w], 1);
            sorted_src[pos] = __builtin_nontemporal_load(&src[e + 3]);
        }
    }
}

// ---------------- per-layer compute ----------------

// z = x @ W_l (fp16 out) ; r = x @ W_r + b (fp32). Register-tiled fp32 GEMM.
__global__ __launch_bounds__(256) void dense_kernel(
        const float* x,
        const float* __restrict__ wl, const float* __restrict__ wr,
        const float* __restrict__ bl,
        __half* __restrict__ z, float* r, int n_nodes) {
    __shared__ float s_w[C][2 * C];
    __shared__ float s_x[64][C + 1];

    const int t = threadIdx.x;
    const int base = blockIdx.x * 64;

    for (int i = t; i < C * C; i += 256) {
        int k = i >> 6, c = i & 63;
        s_w[k][c] = wl[i];
        s_w[k][64 + c] = wr[i];
    }
    for (int i = t; i < 1024; i += 256) {
        int n = i >> 4;
        int kq = i & 15;
        float4 v = make_float4(0.f, 0.f, 0.f, 0.f);
        if (base + n < n_nodes) v = ((const float4*)x)[((size_t)(base + n) << 4) + kq];
        s_x[n][kq * 4 + 0] = v.x;
        s_x[n][kq * 4 + 1] = v.y;
        s_x[n][kq * 4 + 2] = v.z;
        s_x[n][kq * 4 + 3] = v.w;
    }
    __syncthreads();

    const int lane = t & 63;
    const int wv = t >> 6;
    const int cg = lane & 15;
    const int q = lane >> 4;
    const int n0 = wv * 16 + 4 * q;

    float4 bv = ((const float4*)bl)[cg];
    float accz[4][4];
    float accr[4][4];
#pragma unroll
    for (int i = 0; i < 4; ++i) {
        accz[i][0] = accz[i][1] = accz[i][2] = accz[i][3] = 0.f;
        accr[i][0] = bv.x; accr[i][1] = bv.y; accr[i][2] = bv.z; accr[i][3] = bv.w;
    }

#pragma unroll 8
    for (int k = 0; k < C; ++k) {
        float4 wlv = *(const float4*)&s_w[k][4 * cg];
        float4 wrv = *(const float4*)&s_w[k][64 + 4 * cg];
        float xk[4];
#pragma unroll
        for (int i = 0; i < 4; ++i) xk[i] = s_x[n0 + i][k];
#pragma unroll
        for (int i = 0; i < 4; ++i) {
            accz[i][0] += xk[i] * wlv.x;
            accz[i][1] += xk[i] * wlv.y;
            accz[i][2] += xk[i] * wlv.z;
            accz[i][3] += xk[i] * wlv.w;
            accr[i][0] += xk[i] * wrv.x;
            accr[i][1] += xk[i] * wrv.y;
            accr[i][2] += xk[i] * wrv.z;
            accr[i][3] += xk[i] * wrv.w;
        }
    }

#pragma unroll
    for (int i = 0; i < 4; ++i) {
        size_t gn = (size_t)base + n0 + i;
        if (gn < (size_t)n_nodes) {
            __half2 p0 = __float22half2_rn(make_float2(accz[i][0], accz[i][1]));
            __half2 p1 = __float22half2_rn(make_float2(accz[i][2], accz[i][3]));
            ((__half2*)z)[gn * 32 + 2 * cg + 0] = p0;
            ((__half2*)z)[gn * 32 + 2 * cg + 1] = p1;
            ((float4*)r)[gn * 16 + cg] = make_float4(accr[i][0], accr[i][1], accr[i][2], accr[i][3]);
        }
    }
}

// h = PReLU( mean_j z[nbr_j] + r ). Wave = 1 node; each half-wave (32 lanes)
// processes a different neighbor, lane covers 2 channels via __half2 ->
// 16 rows in flight per wave, half the per-lane VALU per edge. Streaming
// traffic (sorted_src, r, out) is non-temporal so the hot 12.8 MB z-table
// keeps L2 residency.
__global__ __launch_bounds__(256) void gather_kernel(
        const __half* __restrict__ z,
        const float* r,
        const int* __restrict__ offsets,
        const int* __restrict__ sorted_src,
        const float* __restrict__ a,
        float* out) {
    const int lane = threadIdx.x & 63;
    const int node = (blockIdx.x << 2) + (threadIdx.x >> 6);
    const int h = lane >> 5;   // which half-wave
    const int m = lane & 31;   // channel pair: channels 2m, 2m+1

    const int beg = offsets[node];
    const int deg = offsets[node + 1] - beg;
    const int last = deg - 1;

    const __half2* zz = (const __half2*)z;
    float ax = 0.0f, ay = 0.0f;
    for (int base = 0; base < deg; base += 16) {
        int idx[8];
#pragma unroll
        for (int i = 0; i < 8; ++i)
            idx[i] = __builtin_nontemporal_load(&sorted_src[beg + min(base + 2 * i + h, last)]);
        __half2 v[8];
#pragma unroll
        for (int i = 0; i < 8; ++i)
            v[i] = zz[(size_t)idx[i] * 32 + m];
#pragma unroll
        for (int i = 0; i < 8; ++i) {
            if (base + 2 * i + h < deg) {
                float2 f = __half22float2(v[i]);
                ax += f.x;
                ay += f.y;
            }
        }
    }
    // combine the two half-waves (both halves hold partial sums for the same
    // channel pair m)
    ax += __shfl(ax, lane ^ 32);
    ay += __shfl(ay, lane ^ 32);

    if (h == 0) {
        float degf = (float)max(deg, 1);
        vfloat2 rv = __builtin_nontemporal_load(&((const vfloat2*)r)[(size_t)node * 32 + m]);
        float2 av = ((const float2*)a)[m];
        float hx = ax / degf + rv.x;
        float hy = ay / degf + rv.y;
        vfloat2 o;
        o.x = hx >= 0.0f ? hx : av.x * hx;
        o.y = hy >= 0.0f ? hy : av.y * hy;
        __builtin_nontemporal_store(o, &((vfloat2*)out)[(size_t)node * 32 + m]);
    }
}

extern "C" void kernel_launch(void* const* d_in, const int* in_sizes, int n_in,
                              void* d_out, int out_size, void* d_ws, size_t ws_size,
                              hipStream_t stream) {
    const float* x    = (const float*)d_in[0];
    const int*   ei   = (const int*)d_in[1];
    const float* w_l0 = (const float*)d_in[2];
    const float* b_l0 = (const float*)d_in[3];
    const float* w_r0 = (const float*)d_in[4];
    const float* a0   = (const float*)d_in[5];
    const float* w_l1 = (const float*)d_in[6];
    const float* b_l1 = (const float*)d_in[7];
    const float* w_r1 = (const float*)d_in[8];
    const float* a1   = (const float*)d_in[9];
    float* out = (float*)d_out;

    const int* src = ei;            // edge_index[0, :]
    const int* dst = ei + N_EDGES;  // edge_index[1, :]

    // ws: cnt[N] | partial[512] | offsets[N+1] | cursor[N] | sorted_src[E] | Z(fp16) | B(fp32)
    int* cnt        = (int*)d_ws;
    int* partial    = cnt + N_NODES;
    int* offsets    = partial + 512;
    int* cursor     = offsets + (N_NODES + 1);
    int* sorted_src = cursor + N_NODES;
    __half* Z       = (__half*)(sorted_src + N_EDGES);
    float* B        = (float*)(Z + (size_t)N_NODES * C);

    hipMemsetAsync(cnt, 0, (size_t)N_NODES * sizeof(int), stream);

    const int qblocks = (N_EDGES / 4 + 255) / 256;
    const int nblocks = N_NODES / 4;          // gather grid (exact)
    const int dblocks = (N_NODES + 63) / 64;  // dense grid

    hist_kernel<<<qblocks, 256, 0, stream>>>(dst, cnt);
    scan1_kernel<<<SCAN_NB, 256, 0, stream>>>(cnt, partial);
    scan2_kernel<<<1, 512, 0, stream>>>(partial);
    scan3_kernel<<<SCAN_NB, 256, 0, stream>>>(cnt, partial, offsets, cursor);
    bucket_kernel<<<8 * COHORT, 256, 0, stream>>>(src, dst, cursor, sorted_src);

    // Layer 0: z=Z, r=B; gather writes h1 into B (row-aligned alias with r)
    dense_kernel<<<dblocks, 256, 0, stream>>>(x, w_l0, w_r0, b_l0, Z, B, N_NODES);
    gather_kernel<<<nblocks, 256, 0, stream>>>(Z, B, offsets, sorted_src, a0, B);

    // Layer 1: x=B, z=Z, r=B (in-place per-block safe); gather -> d_out
    dense_kernel<<<dblocks, 256, 0, stream>>>(B, w_l1, w_r1, b_l1, Z, B, N_NODES);
    gather_kernel<<<nblocks, 256, 0, stream>>>(Z, B, offsets, sorted_src, a1, out);
}